// Round 15
// baseline (82.104 us; speedup 1.0000x reference)
//
#include <hip/hip_runtime.h>

#define HH 128
#define WW 192
#define HW (HH * WW)
#define MAXI 64
#define TCOLS 200   // padded logit-tile row stride (floats)

typedef float f32x2v __attribute__((ext_vector_type(2)));
typedef __fp16 h2 __attribute__((ext_vector_type(2)));

__device__ __forceinline__ float relu(float v) { return fmaxf(v, 0.0f); }
__device__ __forceinline__ float fdot2(h2 a, h2 b, float c) {
    return __builtin_amdgcn_fdot2(a, b, c, false);
}
__device__ __forceinline__ h2 pkrtz(float a, float b) {
    return __builtin_amdgcn_cvt_pkrtz(a, b);
}

// Per-instance LDS weight slot:
//   sWp[k][68] (h2):  [0..31] w0feat o*4+p=(w0[o][2+2p],w0[o][3+2p])
//                     [32..63] w1 32+o*4+p   [64..67] w2
//   sF[k][36] (f32):  [0..7] w0x [8..15] w0y [16..23] b0 [24..31] b1
//                     [32] b2 [33] locx [34] locy [35] inv
__global__ __launch_bounds__(256) void dmh_kernel(
    const float* __restrict__ mask_feats,   // (4,8,128,192)
    const float* __restrict__ params,       // (128,169)
    const float* __restrict__ locs,         // (128,2)
    const float* __restrict__ soi,          // (5,)
    const int*   __restrict__ im_inds,      // (128,)
    const int*   __restrict__ fpn_levels,   // (128,)
    const int*   __restrict__ stride_p,     // scalar (=8)
    float*       __restrict__ out)          // (128,1,256,384)
{
    const int tid = threadIdx.x;
    const int g   = blockIdx.x;    // row-pair tile: src rows 2g,2g+1; out rows 4g..4g+3
    const int img = blockIdx.y;    // image 0..3

    __shared__ h2    sWp[MAXI][68];
    __shared__ float sF[MAXI][36];
    __shared__ float tile[2][3 * TCOLS];
    __shared__ int   sList[MAXI];
    __shared__ int   sCnt;

    if (tid == 0) sCnt = 0;
    __syncthreads();
    if (tid < 128 && im_inds[tid] == img) {
        int p = atomicAdd(&sCnt, 1);
        if (p < MAXI) sList[p] = tid;
    }
    __syncthreads();
    const int cnt = min(sCnt, MAXI);

    const int   stride = *stride_p;             // 8
    const float half_s = 0.5f * (float)stride;  // 4.0
    const float* fb = mask_feats + (size_t)img * 8 * HW;

    // ---- own-px feat loads (ONCE per block; reused for all instances) ----
    // px p in [0,576): tilerow = p/192 (src row clamp(2g-1+tr)), col = p%192
    // thread owns p = tid, tid+256, and (tid<64) tid+512
    const int nPx = (tid < 64) ? 3 : 2;
    int  trow[3]; int tcol[3];
    float cpos[3], rpos[3];
    h2 xp[3][4];
    #pragma unroll
    for (int j = 0; j < 3; ++j) {
        if (j < nPx) {
            int p  = tid + 256 * j;
            int tr = p / 192, c = p - tr * 192;
            int srow = max(2 * g - 1 + tr, 0);
            trow[j] = tr; tcol[j] = c;
            cpos[j] = (float)(c * stride) + half_s;
            rpos[j] = (float)(srow * stride) + half_s;
            const float* fp = fb + srow * WW + c;
            float x0 = fp[0],      x1 = fp[HW],     x2 = fp[2 * HW], x3 = fp[3 * HW];
            float x4 = fp[4 * HW], x5 = fp[5 * HW], x6 = fp[6 * HW], x7 = fp[7 * HW];
            xp[j][0] = pkrtz(x0, x1); xp[j][1] = pkrtz(x2, x3);
            xp[j][2] = pkrtz(x4, x5); xp[j][3] = pkrtz(x6, x7);
        }
    }

    // ---- stage all matching instances' weights (flat, pipelined) ----
    const int total = cnt * 169;
    #pragma unroll 4
    for (int e = tid; e < total; e += 256) {
        int k = e / 169, j = e - k * 169;
        int n = sList[k];
        float v = params[(size_t)n * 169 + j];
        __fp16* sWh = reinterpret_cast<__fp16*>(sWp[k]);
        float*  f   = sF[k];
        if (j < 80) {
            int o = j / 10, r = j - o * 10;
            if (r == 0)      f[o] = v;
            else if (r == 1) f[8 + o] = v;
            else { int q2 = r - 2; sWh[(o * 4 + (q2 >> 1)) * 2 + (q2 & 1)] = (__fp16)v; }
        } else if (j < 144) { int t = j - 80, o = t >> 3, i = t & 7;
                              sWh[(32 + o * 4 + (i >> 1)) * 2 + (i & 1)] = (__fp16)v; }
        else if (j < 152)   { int o = j - 144; sWh[(64 + (o >> 1)) * 2 + (o & 1)] = (__fp16)v; }
        else if (j < 160)   f[16 + (j - 152)] = v;
        else if (j < 168)   f[24 + (j - 160)] = v;
        else                f[32] = v;
    }
    if (tid < cnt) {
        int n = sList[tid];
        sF[tid][33] = locs[2 * n];
        sF[tid][34] = locs[2 * n + 1];
        sF[tid][35] = 1.0f / soi[fpn_levels[n]];
    }
    __syncthreads();

    // ---- constant upsample geometry: thread -> (out row orow, col group q) ----
    const int orow = tid >> 6;          // 0..3
    const int q    = tid & 63;          // out cols 6q..6q+5
    const int y    = 4 * g + orow;
    const int iy   = y - 1;
    const int rb   = iy >> 1;           // arithmetic shift handles iy=-1
    const int fy   = iy & 1;
    const float wy0 = fy ? 0.5f : 1.0f;
    const float wy1 = fy ? 0.5f : 0.0f;
    const int lr   = rb - 2 * g + 1;    // 0..2
    const int lr2  = lr + fy;           // 0..2
    const int c3   = 3 * q;             // src cols c3-1..c3+2
    const int cm   = max(c3 - 1, 0);

    auto upsample = [&](int ki, int b) {
        const float* ta = &tile[b][lr  * TCOLS];
        const float* tb = &tile[b][lr2 * TCOLS];
        float sm = fmaf(wy1, tb[cm],     wy0 * ta[cm]);
        float s0 = fmaf(wy1, tb[c3],     wy0 * ta[c3]);
        float s1 = fmaf(wy1, tb[c3 + 1], wy0 * ta[c3 + 1]);
        float s2 = fmaf(wy1, tb[c3 + 2], wy0 * ta[c3 + 2]);
        const int n = sList[ki];
        float* p = out + ((size_t)n * 256 + y) * 384 + 6 * q;
        f32x2v v0 = {0.5f * (sm + s0), s0};
        f32x2v v1 = {0.5f * (s0 + s1), s1};
        f32x2v v2 = {0.5f * (s1 + s2), s2};
        __builtin_nontemporal_store(v0, reinterpret_cast<f32x2v*>(p));
        __builtin_nontemporal_store(v1, reinterpret_cast<f32x2v*>(p + 2));
        __builtin_nontemporal_store(v2, reinterpret_cast<f32x2v*>(p + 4));
    };

    // ---- instance loop: MLP inst k -> tile[k&1]; upsample inst k-1 ----
    for (int k = 0; k < cnt; ++k) {
        const int buf = k & 1;
        {
            const float lx = sF[k][33], ly = sF[k][34], inv = sF[k][35];
            const float b2v = sF[k][32];
            #pragma unroll
            for (int j = 0; j < 3; ++j) {
                if (j < nPx) {
                    float rx = (lx - cpos[j]) * inv;
                    float ry = (ly - rpos[j]) * inv;
                    float hh[8];
                    #pragma unroll
                    for (int o = 0; o < 8; ++o) {
                        const h2* wr = &sWp[k][o * 4];
                        float acc = fmaf(sF[k][o], rx, fmaf(sF[k][8 + o], ry, sF[k][16 + o]));
                        acc = fdot2(wr[0], xp[j][0], acc);
                        acc = fdot2(wr[1], xp[j][1], acc);
                        acc = fdot2(wr[2], xp[j][2], acc);
                        acc = fdot2(wr[3], xp[j][3], acc);
                        hh[o] = acc;
                    }
                    h2 hp0 = pkrtz(relu(hh[0]), relu(hh[1]));
                    h2 hp1 = pkrtz(relu(hh[2]), relu(hh[3]));
                    h2 hp2 = pkrtz(relu(hh[4]), relu(hh[5]));
                    h2 hp3 = pkrtz(relu(hh[6]), relu(hh[7]));
                    float aa[8];
                    #pragma unroll
                    for (int o = 0; o < 8; ++o) {
                        const h2* wr = &sWp[k][32 + o * 4];
                        float acc = sF[k][24 + o];
                        acc = fdot2(wr[0], hp0, acc);
                        acc = fdot2(wr[1], hp1, acc);
                        acc = fdot2(wr[2], hp2, acc);
                        acc = fdot2(wr[3], hp3, acc);
                        aa[o] = acc;
                    }
                    h2 a0 = pkrtz(relu(aa[0]), relu(aa[1]));
                    h2 a1 = pkrtz(relu(aa[2]), relu(aa[3]));
                    h2 a2 = pkrtz(relu(aa[4]), relu(aa[5]));
                    h2 a3 = pkrtz(relu(aa[6]), relu(aa[7]));
                    float lg = b2v;
                    lg = fdot2(sWp[k][64], a0, lg);
                    lg = fdot2(sWp[k][65], a1, lg);
                    lg = fdot2(sWp[k][66], a2, lg);
                    lg = fdot2(sWp[k][67], a3, lg);
                    tile[buf][trow[j] * TCOLS + tcol[j]] = lg;
                }
            }
        }
        if (k > 0) upsample(k - 1, buf ^ 1);
        __syncthreads();
    }
    if (cnt > 0) upsample(cnt - 1, (cnt - 1) & 1);
}

extern "C" void kernel_launch(void* const* d_in, const int* in_sizes, int n_in,
                              void* d_out, int out_size, void* d_ws, size_t ws_size,
                              hipStream_t stream) {
    const float* mask_feats = (const float*)d_in[0];
    const float* params     = (const float*)d_in[1];
    const float* locs       = (const float*)d_in[2];
    const float* soi        = (const float*)d_in[3];
    const int*   im_inds    = (const int*)d_in[4];
    const int*   fpn_levels = (const int*)d_in[5];
    const int*   stride_p   = (const int*)d_in[6];
    float* out = (float*)d_out;

    dim3 grid(64, 4);    // 64 row-pair tiles x 4 images = 256 blocks
    dim3 block(256);
    dmh_kernel<<<grid, block, 0, stream>>>(
        mask_feats, params, locs, soi, im_inds, fpn_levels, stride_p, out);
}

// Round 16
// 45.258 us; speedup vs baseline: 1.8141x; 1.8141x over previous
//
#include <hip/hip_runtime.h>

#define HH 128
#define WW 192
#define HW (HH * WW)

typedef float f32x4 __attribute__((ext_vector_type(4)));
typedef __fp16 h2 __attribute__((ext_vector_type(2)));

__device__ __forceinline__ float relu(float v) { return fmaxf(v, 0.0f); }

__device__ __forceinline__ float fdot2(h2 a, h2 b, float c) {
    return __builtin_amdgcn_fdot2(a, b, c, false);
}
__device__ __forceinline__ h2 pkrtz(float a, float b) {
    return __builtin_amdgcn_cvt_pkrtz(a, b);
}

// DIAGNOSTIC ROUND: grid.z = 3*128; n = z % 128 -> three identical copies of
// the full problem in one dispatch (~62us) so the kernel beats the harness's
// 40-44us poison-fill dispatches into rocprof's top-5 and we finally get
// VALUBusy/Occupancy/FETCH/WRITE for the 20.4us plateau structure (R11).

__global__ __launch_bounds__(512) void dmh_kernel(
    const float* __restrict__ mask_feats,   // (4,8,128,192)
    const float* __restrict__ params,       // (128,169)
    const float* __restrict__ locs,         // (128,2)
    const float* __restrict__ soi,          // (5,)
    const int*   __restrict__ im_inds,      // (128,)
    const int*   __restrict__ fpn_levels,   // (128,)
    const int*   __restrict__ stride_p,     // scalar (=8)
    float*       __restrict__ out)          // (128,1,256,384)
{
    const int tid = threadIdx.x;
    const int c0 = blockIdx.x * 64;   // source col tile origin
    const int r0 = blockIdx.y * 32;   // source row tile origin
    const int n  = blockIdx.z % 128;  // instance (3 duplicate copies)

    __shared__ h2    sWp[68];
    __shared__ float sF[33];
    __shared__ float tile[33 * 66];   // rows -1..31 -> 0..32, cols -1..63 -> 0..64

    // ---- stage weights: fp16-pack matmul weights, fp32 for coords/biases ----
    if (tid < 169) {
        float v = params[(size_t)n * 169 + tid];
        __fp16* sWh = reinterpret_cast<__fp16*>(sWp);
        if (tid < 80) {
            int o = tid / 10, k = tid - o * 10;
            if (k == 0)      sF[o] = v;
            else if (k == 1) sF[8 + o] = v;
            else { int f = k - 2; sWh[(o * 4 + (f >> 1)) * 2 + (f & 1)] = (__fp16)v; }
        } else if (tid < 144) {
            int t = tid - 80, o = t >> 3, i = t & 7;
            sWh[(32 + o * 4 + (i >> 1)) * 2 + (i & 1)] = (__fp16)v;
        } else if (tid < 152) {
            int o = tid - 144;
            sWh[(64 + (o >> 1)) * 2 + (o & 1)] = (__fp16)v;
        } else if (tid < 160) sF[16 + (tid - 152)] = v;   // b0
        else if (tid < 168)   sF[24 + (tid - 160)] = v;   // b1
        else                  sF[32] = v;                  // b2
    }

    const int   stride = *stride_p;                 // 8
    const float half_s = 0.5f * (float)stride;      // 4.0
    const float locx = locs[2 * n + 0];
    const float locy = locs[2 * n + 1];
    const float inv  = 1.0f / soi[fpn_levels[n]];
    const float* fb  = mask_feats + (size_t)im_inds[n] * 8 * HW;

    // ---- interior geometry: 1 row x 4 cols per thread; loads pre-barrier ----
    const int ir = tid >> 4;          // 0..31
    const int ic = (tid & 15) << 2;   // 0,4,...,60
    const int rr = r0 + ir, cc = c0 + ic;
    const float* fp = fb + rr * WW + cc;

    f32x4 xv[8];
    #pragma unroll
    for (int ch = 0; ch < 8; ++ch)
        xv[ch] = *reinterpret_cast<const f32x4*>(fp + ch * HW);

    __syncthreads();

    // ---------- phase 1a: interior MLP via v_dot2_f32_f16 ----------
    {
        const float rxd = -(float)stride * inv;
        float rx[4];
        rx[0] = (locx - (float)(cc * stride) - half_s) * inv;
        rx[1] = rx[0] + rxd; rx[2] = rx[1] + rxd; rx[3] = rx[2] + rxd;
        const float ry = (locy - (float)(rr * stride) - half_s) * inv;

        h2 xp[4][4];
        #pragma unroll
        for (int p = 0; p < 4; ++p)
            #pragma unroll
            for (int j = 0; j < 4; ++j)
                xp[p][j] = pkrtz(xv[2 * p][j], xv[2 * p + 1][j]);

        float h[8][4];
        #pragma unroll
        for (int o = 0; o < 8; ++o) {
            const h2 w0 = sWp[o * 4 + 0], w1 = sWp[o * 4 + 1],
                     w2 = sWp[o * 4 + 2], w3 = sWp[o * 4 + 3];
            float tO = fmaf(sF[8 + o], ry, sF[16 + o]);
            float wx = sF[o];
            #pragma unroll
            for (int j = 0; j < 4; ++j) {
                float acc = fmaf(wx, rx[j], tO);
                acc = fdot2(w0, xp[0][j], acc);
                acc = fdot2(w1, xp[1][j], acc);
                acc = fdot2(w2, xp[2][j], acc);
                acc = fdot2(w3, xp[3][j], acc);
                h[o][j] = acc;
            }
        }

        h2 hp[4][4];
        #pragma unroll
        for (int p = 0; p < 4; ++p)
            #pragma unroll
            for (int j = 0; j < 4; ++j)
                hp[p][j] = pkrtz(relu(h[2 * p][j]), relu(h[2 * p + 1][j]));

        float a[8][4];
        #pragma unroll
        for (int o = 0; o < 8; ++o) {
            const h2 w0 = sWp[32 + o * 4 + 0], w1 = sWp[32 + o * 4 + 1],
                     w2 = sWp[32 + o * 4 + 2], w3 = sWp[32 + o * 4 + 3];
            float b1 = sF[24 + o];
            #pragma unroll
            for (int j = 0; j < 4; ++j) {
                float acc = b1;
                acc = fdot2(w0, hp[0][j], acc);
                acc = fdot2(w1, hp[1][j], acc);
                acc = fdot2(w2, hp[2][j], acc);
                acc = fdot2(w3, hp[3][j], acc);
                a[o][j] = acc;
            }
        }

        const h2 v0 = sWp[64], v1 = sWp[65], v2 = sWp[66], v3 = sWp[67];
        const float b2v = sF[32];
        #pragma unroll
        for (int j = 0; j < 4; ++j) {
            h2 a0 = pkrtz(relu(a[0][j]), relu(a[1][j]));
            h2 a1 = pkrtz(relu(a[2][j]), relu(a[3][j]));
            h2 a2 = pkrtz(relu(a[4][j]), relu(a[5][j]));
            h2 a3 = pkrtz(relu(a[6][j]), relu(a[7][j]));
            float lg = b2v;
            lg = fdot2(v0, a0, lg);
            lg = fdot2(v1, a1, lg);
            lg = fdot2(v2, a2, lg);
            lg = fdot2(v3, a3, lg);
            tile[(ir + 1) * 66 + ic + 1 + j] = lg;
        }
    }

    // ---------- phase 1b: 97 halo px, same fp16-dot2 math, 1 px ----------
    if (tid < 97) {
        int r, c;
        if (tid < 65) { r = -1; c = tid - 1; }      // row -1, cols -1..63
        else          { r = tid - 65; c = -1; }     // rows 0..31, col -1
        int hr = min(max(r0 + r, 0), HH - 1);
        int hc = min(max(c0 + c, 0), WW - 1);
        const float* hfp = fb + hr * WW + hc;
        float rx  = (locx - (float)(hc * stride) - half_s) * inv;
        float ry2 = (locy - (float)(hr * stride) - half_s) * inv;
        h2 xp[4];
        #pragma unroll
        for (int p = 0; p < 4; ++p)
            xp[p] = pkrtz(hfp[(2 * p) * HW], hfp[(2 * p + 1) * HW]);
        float hh[8];
        #pragma unroll
        for (int o = 0; o < 8; ++o) {
            float acc = fmaf(sF[o], rx, fmaf(sF[8 + o], ry2, sF[16 + o]));
            #pragma unroll
            for (int p = 0; p < 4; ++p) acc = fdot2(sWp[o * 4 + p], xp[p], acc);
            hh[o] = acc;
        }
        h2 hp[4];
        #pragma unroll
        for (int p = 0; p < 4; ++p)
            hp[p] = pkrtz(relu(hh[2 * p]), relu(hh[2 * p + 1]));
        float aa[8];
        #pragma unroll
        for (int o = 0; o < 8; ++o) {
            float acc = sF[24 + o];
            #pragma unroll
            for (int p = 0; p < 4; ++p) acc = fdot2(sWp[32 + o * 4 + p], hp[p], acc);
            aa[o] = acc;
        }
        float lg = sF[32];
        #pragma unroll
        for (int p = 0; p < 4; ++p) {
            h2 ap = pkrtz(relu(aa[2 * p]), relu(aa[2 * p + 1]));
            lg = fdot2(sWp[64 + p], ap, lg);
        }
        tile[(r + 1) * 66 + (c + 1)] = lg;
    }
    __syncthreads();

    // ---------- phase 2: x2 aligned upsample -> 64x128 output tile ----------
    const int kx = tid & 31;          // 32 groups of 4 output cols
    const int ky = tid >> 5;          // 16 row groups of 4 rows
    float* ob = out + ((size_t)n * 256 + 2 * r0) * 384 + 2 * c0 + 4 * kx;
    #pragma unroll
    for (int yy = 0; yy < 4; ++yy) {
        int yt = ky * 4 + yy;         // 0..63
        int iy = yt - 1;
        int rbl = iy >> 1;            // arithmetic shift handles iy=-1
        int fy = iy & 1;
        float wy0 = fy ? 0.5f : 1.0f;
        float wy1 = fy ? 0.5f : 0.0f;
        int sr  = rbl + 1;            // in [0,32]
        int sr2 = sr + fy;            // in [0,32]
        const float* ra = &tile[sr  * 66 + 2 * kx];
        const float* rc = &tile[sr2 * 66 + 2 * kx];
        float t0 = fmaf(wy1, rc[0], wy0 * ra[0]);
        float t1 = fmaf(wy1, rc[1], wy0 * ra[1]);
        float t2 = fmaf(wy1, rc[2], wy0 * ra[2]);
        f32x4 o4;
        o4.x = 0.5f * (t0 + t1);
        o4.y = t1;
        o4.z = 0.5f * (t1 + t2);
        o4.w = t2;
        __builtin_nontemporal_store(o4, reinterpret_cast<f32x4*>(ob + (size_t)yt * 384));
    }
}

extern "C" void kernel_launch(void* const* d_in, const int* in_sizes, int n_in,
                              void* d_out, int out_size, void* d_ws, size_t ws_size,
                              hipStream_t stream) {
    const float* mask_feats = (const float*)d_in[0];
    const float* params     = (const float*)d_in[1];
    const float* locs       = (const float*)d_in[2];
    const float* soi        = (const float*)d_in[3];
    const int*   im_inds    = (const int*)d_in[4];
    const int*   fpn_levels = (const int*)d_in[5];
    const int*   stride_p   = (const int*)d_in[6];
    float* out = (float*)d_out;

    dim3 grid(WW / 64, HH / 32, 3 * 128);   // 3 identical copies (diagnostic)
    dim3 block(512);
    dmh_kernel<<<grid, block, 0, stream>>>(
        mask_feats, params, locs, soi, im_inds, fpn_levels, stride_p, out);
}

// Round 17
// 20.083 us; speedup vs baseline: 4.0881x; 2.2535x over previous
//
#include <hip/hip_runtime.h>

#define HH 128
#define WW 192
#define HW (HH * WW)

typedef float f32x4 __attribute__((ext_vector_type(4)));
typedef float f32x2v __attribute__((ext_vector_type(2)));
typedef __fp16 h2 __attribute__((ext_vector_type(2)));

__device__ __forceinline__ float relu(float v) { return fmaxf(v, 0.0f); }
__device__ __forceinline__ float fdot2(h2 a, h2 b, float c) {
    return __builtin_amdgcn_fdot2(a, b, c, false);
}
__device__ __forceinline__ h2 pkrtz(float a, float b) {
    return __builtin_amdgcn_cvt_pkrtz(a, b);
}
// packed relu on an f16 pair (v_pk_max_f16)
__device__ __forceinline__ h2 prelu2(h2 v) {
    h2 z = {(__fp16)0.0f, (__fp16)0.0f};
    return __builtin_elementwise_max(v, z);
}

// LDS packed-weight layout:
//   sWp (h2): [0..31] w0feat o*4+p=(w0[o][2+2p],w0[o][3+2p])
//             [32..63] w1 32+o*4+p=(w1[o][2p],w1[o][2p+1])
//             [64..67] w2 64+p=(w2[2p],w2[2p+1])
//   sF (f32): [0..7] w0x [8..15] w0y [16..23] b0 [24..31] b1 [32] b2

__global__ __launch_bounds__(512) void dmh_kernel(
    const float* __restrict__ mask_feats,   // (4,8,128,192)
    const float* __restrict__ params,       // (128,169)
    const float* __restrict__ locs,         // (128,2)
    const float* __restrict__ soi,          // (5,)
    const int*   __restrict__ im_inds,      // (128,)
    const int*   __restrict__ fpn_levels,   // (128,)
    const int*   __restrict__ stride_p,     // scalar (=8)
    float*       __restrict__ out)          // (128,1,256,384)
{
    const int tid = threadIdx.x;
    const int c0 = blockIdx.x * 64;   // source col tile origin
    const int r0 = blockIdx.y * 32;   // source row tile origin
    const int n  = blockIdx.z;        // instance

    __shared__ h2    sWp[68];
    __shared__ float sF[33];
    __shared__ float tile[33 * 66];   // rows -1..31 -> 0..32, cols -1..63 -> 0..64

    // ---- stage weights: fp16-pack matmul weights, fp32 for coords/biases ----
    if (tid < 169) {
        float v = params[(size_t)n * 169 + tid];
        __fp16* sWh = reinterpret_cast<__fp16*>(sWp);
        if (tid < 80) {
            int o = tid / 10, k = tid - o * 10;
            if (k == 0)      sF[o] = v;
            else if (k == 1) sF[8 + o] = v;
            else { int f = k - 2; sWh[(o * 4 + (f >> 1)) * 2 + (f & 1)] = (__fp16)v; }
        } else if (tid < 144) {
            int t = tid - 80, o = t >> 3, i = t & 7;
            sWh[(32 + o * 4 + (i >> 1)) * 2 + (i & 1)] = (__fp16)v;
        } else if (tid < 152) {
            int o = tid - 144;
            sWh[(64 + (o >> 1)) * 2 + (o & 1)] = (__fp16)v;
        } else if (tid < 160) sF[16 + (tid - 152)] = v;   // b0
        else if (tid < 168)   sF[24 + (tid - 160)] = v;   // b1
        else                  sF[32] = v;                  // b2
    }

    const int   stride = *stride_p;                 // 8
    const float half_s = 0.5f * (float)stride;      // 4.0
    const float locx = locs[2 * n + 0];
    const float locy = locs[2 * n + 1];
    const float inv  = 1.0f / soi[fpn_levels[n]];
    const float* fb  = mask_feats + (size_t)im_inds[n] * 8 * HW;

    // ---- interior geometry: 1 row x 4 cols per thread; loads pre-barrier ----
    const int ir = tid >> 4;          // 0..31
    const int ic = (tid & 15) << 2;   // 0,4,...,60
    const int rr = r0 + ir, cc = c0 + ic;
    const float* fp = fb + rr * WW + cc;

    f32x4 xv[8];
    #pragma unroll
    for (int ch = 0; ch < 8; ++ch)
        xv[ch] = *reinterpret_cast<const f32x4*>(fp + ch * HW);

    __syncthreads();

    // ---------- phase 1a: interior MLP via v_dot2_f32_f16 ----------
    {
        const float rxd = -(float)stride * inv;
        float rx[4];
        rx[0] = (locx - (float)(cc * stride) - half_s) * inv;
        rx[1] = rx[0] + rxd; rx[2] = rx[1] + rxd; rx[3] = rx[2] + rxd;
        const float ry = (locy - (float)(rr * stride) - half_s) * inv;

        h2 xp[4][4];
        #pragma unroll
        for (int p = 0; p < 4; ++p)
            #pragma unroll
            for (int j = 0; j < 4; ++j)
                xp[p][j] = pkrtz(xv[2 * p][j], xv[2 * p + 1][j]);

        float h[8][4];
        #pragma unroll
        for (int o = 0; o < 8; ++o) {
            const h2 w0 = sWp[o * 4 + 0], w1 = sWp[o * 4 + 1],
                     w2 = sWp[o * 4 + 2], w3 = sWp[o * 4 + 3];
            float tO = fmaf(sF[8 + o], ry, sF[16 + o]);
            float wx = sF[o];
            #pragma unroll
            for (int j = 0; j < 4; ++j) {
                float acc = fmaf(wx, rx[j], tO);
                acc = fdot2(w0, xp[0][j], acc);
                acc = fdot2(w1, xp[1][j], acc);
                acc = fdot2(w2, xp[2][j], acc);
                acc = fdot2(w3, xp[3][j], acc);
                h[o][j] = acc;
            }
        }

        h2 hp[4][4];
        #pragma unroll
        for (int p = 0; p < 4; ++p)
            #pragma unroll
            for (int j = 0; j < 4; ++j)
                hp[p][j] = prelu2(pkrtz(h[2 * p][j], h[2 * p + 1][j]));

        float a[8][4];
        #pragma unroll
        for (int o = 0; o < 8; ++o) {
            const h2 w0 = sWp[32 + o * 4 + 0], w1 = sWp[32 + o * 4 + 1],
                     w2 = sWp[32 + o * 4 + 2], w3 = sWp[32 + o * 4 + 3];
            float b1 = sF[24 + o];
            #pragma unroll
            for (int j = 0; j < 4; ++j) {
                float acc = b1;
                acc = fdot2(w0, hp[0][j], acc);
                acc = fdot2(w1, hp[1][j], acc);
                acc = fdot2(w2, hp[2][j], acc);
                acc = fdot2(w3, hp[3][j], acc);
                a[o][j] = acc;
            }
        }

        const h2 v0 = sWp[64], v1 = sWp[65], v2 = sWp[66], v3 = sWp[67];
        const float b2v = sF[32];
        #pragma unroll
        for (int j = 0; j < 4; ++j) {
            h2 a0 = prelu2(pkrtz(a[0][j], a[1][j]));
            h2 a1 = prelu2(pkrtz(a[2][j], a[3][j]));
            h2 a2 = prelu2(pkrtz(a[4][j], a[5][j]));
            h2 a3 = prelu2(pkrtz(a[6][j], a[7][j]));
            float lg = b2v;
            lg = fdot2(v0, a0, lg);
            lg = fdot2(v1, a1, lg);
            lg = fdot2(v2, a2, lg);
            lg = fdot2(v3, a3, lg);
            tile[(ir + 1) * 66 + ic + 1 + j] = lg;
        }
    }

    // ---------- phase 1b: 97 halo px, same fp16-dot2 math, 1 px ----------
    if (tid < 97) {
        int r, c;
        if (tid < 65) { r = -1; c = tid - 1; }      // row -1, cols -1..63
        else          { r = tid - 65; c = -1; }     // rows 0..31, col -1
        int hr = min(max(r0 + r, 0), HH - 1);
        int hc = min(max(c0 + c, 0), WW - 1);
        const float* hfp = fb + hr * WW + hc;
        float rx  = (locx - (float)(hc * stride) - half_s) * inv;
        float ry2 = (locy - (float)(hr * stride) - half_s) * inv;
        h2 xp[4];
        #pragma unroll
        for (int p = 0; p < 4; ++p)
            xp[p] = pkrtz(hfp[(2 * p) * HW], hfp[(2 * p + 1) * HW]);
        float hh[8];
        #pragma unroll
        for (int o = 0; o < 8; ++o) {
            float acc = fmaf(sF[o], rx, fmaf(sF[8 + o], ry2, sF[16 + o]));
            #pragma unroll
            for (int p = 0; p < 4; ++p) acc = fdot2(sWp[o * 4 + p], xp[p], acc);
            hh[o] = acc;
        }
        h2 hp[4];
        #pragma unroll
        for (int p = 0; p < 4; ++p)
            hp[p] = prelu2(pkrtz(hh[2 * p], hh[2 * p + 1]));
        float aa[8];
        #pragma unroll
        for (int o = 0; o < 8; ++o) {
            float acc = sF[24 + o];
            #pragma unroll
            for (int p = 0; p < 4; ++p) acc = fdot2(sWp[32 + o * 4 + p], hp[p], acc);
            aa[o] = acc;
        }
        float lg = sF[32];
        #pragma unroll
        for (int p = 0; p < 4; ++p) {
            h2 ap = prelu2(pkrtz(aa[2 * p], aa[2 * p + 1]));
            lg = fdot2(sWp[64 + p], ap, lg);
        }
        tile[(r + 1) * 66 + (c + 1)] = lg;
    }
    __syncthreads();

    // ---------- phase 2: x2 aligned upsample, conflict-free ----------
    // wave w owns 8 output rows (yt = w*8..w*8+7), uniform tile row per iter;
    // lane k covers local out cols 2k,2k+1 from tile cols k,k+1 (stride-1 reads
    // = 2-way bank alias = free; merges to ds_read2_b32); 8B coalesced stores.
    {
        const int lane = tid & 63;
        const int wv   = tid >> 6;        // 0..7
        float* ob = out + ((size_t)n * 256 + 2 * r0) * 384 + 2 * c0 + 2 * lane;
        #pragma unroll
        for (int i = 0; i < 8; ++i) {
            int yt  = wv * 8 + i;         // 0..63
            int iy  = yt - 1;
            int fy  = iy & 1;
            int sr  = (iy >> 1) + 1;      // tile row 0..32 (arith shift: yt=0 -> 0)
            const float* ta = &tile[sr * 66 + lane];
            float t0, t1;
            if (fy) {
                const float* tb = ta + 66;
                t0 = 0.5f * (ta[0] + tb[0]);
                t1 = 0.5f * (ta[1] + tb[1]);
            } else {
                t0 = ta[0];
                t1 = ta[1];
            }
            f32x2v o2 = {0.5f * (t0 + t1), t1};
            __builtin_nontemporal_store(o2,
                reinterpret_cast<f32x2v*>(ob + (size_t)yt * 384));
        }
    }
}

extern "C" void kernel_launch(void* const* d_in, const int* in_sizes, int n_in,
                              void* d_out, int out_size, void* d_ws, size_t ws_size,
                              hipStream_t stream) {
    const float* mask_feats = (const float*)d_in[0];
    const float* params     = (const float*)d_in[1];
    const float* locs       = (const float*)d_in[2];
    const float* soi        = (const float*)d_in[3];
    const int*   im_inds    = (const int*)d_in[4];
    const int*   fpn_levels = (const int*)d_in[5];
    const int*   stride_p   = (const int*)d_in[6];
    float* out = (float*)d_out;

    dim3 grid(WW / 64, HH / 32, 128);   // (3, 4, 128)
    dim3 block(512);
    dmh_kernel<<<grid, block, 0, stream>>>(
        mask_feats, params, locs, soi, im_inds, fpn_levels, stride_p, out);
}